// Round 3
// baseline (647.987 us; speedup 1.0000x reference)
//
#include <hip/hip_runtime.h>
#include <math.h>

#define BB 256
#define SS 256
#define KK 64
#define DD 128

typedef short bf16x8 __attribute__((ext_vector_type(8)));
typedef float f32x4 __attribute__((ext_vector_type(4)));

__device__ __forceinline__ unsigned short bf16_rne(float x) {
  unsigned u = __float_as_uint(x);
  unsigned r = ((u >> 16) & 1u) + 0x7fffu;
  return (unsigned short)((u + r) >> 16);
}

// ---------------------------------------------------------------------------
// Precompute 1: kV[b,k,e] = sum_d keys[b,k,d] * V[d,e]   (fp32)
// ---------------------------------------------------------------------------
__global__ __launch_bounds__(256) void kv_kernel(const float* __restrict__ keys,
                                                 const float* __restrict__ V,
                                                 float* __restrict__ kV)
{
    __shared__ __align__(16) float Ks[KK][DD];
    __shared__ __align__(16) float Vs[DD][DD];
    const int b = blockIdx.x;
    const int t = threadIdx.x;
    const float* kb = keys + (size_t)b * KK * DD;
    for (int i = t; i < KK * DD / 4; i += 256) ((float4*)Ks)[i] = ((const float4*)kb)[i];
    for (int i = t; i < DD * DD / 4; i += 256) ((float4*)Vs)[i] = ((const float4*)V)[i];
    __syncthreads();

    const int e0 = (t & 15) * 8;
    const int k0 = (t >> 4) * 4;
    float acc[4][8];
#pragma unroll
    for (int i = 0; i < 4; ++i)
#pragma unroll
        for (int j = 0; j < 8; ++j) acc[i][j] = 0.f;

#pragma unroll 4
    for (int d = 0; d < DD; ++d) {
        float aa[4] = {Ks[k0 + 0][d], Ks[k0 + 1][d], Ks[k0 + 2][d], Ks[k0 + 3][d]};
        float4 v0 = *(const float4*)&Vs[d][e0];
        float4 v1 = *(const float4*)&Vs[d][e0 + 4];
        float vv[8] = {v0.x, v0.y, v0.z, v0.w, v1.x, v1.y, v1.z, v1.w};
#pragma unroll
        for (int i = 0; i < 4; ++i)
#pragma unroll
            for (int j = 0; j < 8; ++j) acc[i][j] = fmaf(aa[i], vv[j], acc[i][j]);
    }
    float* o = kV + (size_t)b * KK * DD;
#pragma unroll
    for (int i = 0; i < 4; ++i)
#pragma unroll
        for (int j = 0; j < 8; j += 4) {
            float4 w4 = {acc[i][j], acc[i][j + 1], acc[i][j + 2], acc[i][j + 3]};
            *(float4*)&o[(k0 + i) * DD + e0 + j] = w4;
        }
}

// ---------------------------------------------------------------------------
// Precompute 2 (fused): sW[b,t,e] = enc[b,t,:]@W ; sk[b,t,k] = enc[b,t,:].keys[b,k,:]
// Shares the Es staging between the two products.
// ---------------------------------------------------------------------------
__global__ __launch_bounds__(256) void swsk_kernel(const float* __restrict__ enc,
                                                   const float* __restrict__ W,
                                                   const float* __restrict__ keys,
                                                   float* __restrict__ sW,
                                                   float* __restrict__ sk)
{
    __shared__ __align__(16) float Es[64][DD];   // 32 KB
    __shared__ __align__(16) float Ws[DD][DD];   // 64 KB (phase 2: reused for Ks)
    const int blk = blockIdx.x;
    const int b = blk >> 2;
    const int tt = blk & 3;
    const int t = threadIdx.x;
    const float* eb = enc + ((size_t)b * SS + tt * 64) * DD;
    for (int i = t; i < 64 * DD / 4; i += 256) ((float4*)Es)[i] = ((const float4*)eb)[i];
    for (int i = t; i < DD * DD / 4; i += 256) ((float4*)Ws)[i] = ((const float4*)W)[i];
    __syncthreads();

    // ---- phase 1: sW ----
    {
        const int e0 = (t & 15) * 8;
        const int r0 = (t >> 4) * 4;
        float acc[4][8];
#pragma unroll
        for (int i = 0; i < 4; ++i)
#pragma unroll
            for (int j = 0; j < 8; ++j) acc[i][j] = 0.f;
#pragma unroll 4
        for (int d = 0; d < DD; ++d) {
            float aa[4] = {Es[r0 + 0][d], Es[r0 + 1][d], Es[r0 + 2][d], Es[r0 + 3][d]};
            float4 v0 = *(const float4*)&Ws[d][e0];
            float4 v1 = *(const float4*)&Ws[d][e0 + 4];
            float vv[8] = {v0.x, v0.y, v0.z, v0.w, v1.x, v1.y, v1.z, v1.w};
#pragma unroll
            for (int i = 0; i < 4; ++i)
#pragma unroll
                for (int j = 0; j < 8; ++j) acc[i][j] = fmaf(aa[i], vv[j], acc[i][j]);
        }
        float* o = sW + ((size_t)b * SS + tt * 64) * DD;
#pragma unroll
        for (int i = 0; i < 4; ++i)
#pragma unroll
            for (int j = 0; j < 8; j += 4) {
                float4 w4 = {acc[i][j], acc[i][j + 1], acc[i][j + 2], acc[i][j + 3]};
                *(float4*)&o[(r0 + i) * DD + e0 + j] = w4;
            }
    }
    __syncthreads();
    // ---- phase 2: stage keys over Ws, compute sk ----
    {
        float (*Ks)[DD] = (float(*)[DD])Ws;
        const float* kb = keys + (size_t)b * KK * DD;
        for (int i = t; i < KK * DD / 4; i += 256) ((float4*)Ks)[i] = ((const float4*)kb)[i];
        __syncthreads();

        const int r0 = (t >> 4) * 4;
        const int k0 = (t & 15) * 4;
        float acc[4][4];
#pragma unroll
        for (int i = 0; i < 4; ++i)
#pragma unroll
            for (int j = 0; j < 4; ++j) acc[i][j] = 0.f;
#pragma unroll 4
        for (int d = 0; d < DD; ++d) {
            float er[4], kr[4];
#pragma unroll
            for (int i = 0; i < 4; ++i) er[i] = Es[r0 + i][d];
#pragma unroll
            for (int j = 0; j < 4; ++j) kr[j] = Ks[k0 + j][d];
#pragma unroll
            for (int i = 0; i < 4; ++i)
#pragma unroll
                for (int j = 0; j < 4; ++j) acc[i][j] = fmaf(er[i], kr[j], acc[i][j]);
        }
        float* o = sk + ((size_t)b * SS + tt * 64) * KK;
#pragma unroll
        for (int i = 0; i < 4; ++i) {
            float4 w4 = {acc[i][0], acc[i][1], acc[i][2], acc[i][3]};
            *(float4*)&o[(r0 + i) * KK + k0] = w4;
        }
    }
}

// ---------------------------------------------------------------------------
// Precompute 3: U in MFMA B-fragment order, split bf16 hi/lo.
// Ufh/Ufl layout: [ntg(8)][kt(4)][lane(64)][j(8)], value =
//   U[32*kt + 8*(lane>>4) + j][16*ntg + (lane&15)]
// ---------------------------------------------------------------------------
__global__ void ufrag_kernel(const float* __restrict__ U,
                             unsigned short* __restrict__ Ufh,
                             unsigned short* __restrict__ Ufl)
{
    const int blk = blockIdx.x;       // 32 = ntg*4 + kt
    const int l = threadIdx.x;        // 64
    const int ntg = blk >> 2, kt = blk & 3;
    const int e = ntg * 16 + (l & 15);
    const int d0 = kt * 32 + (l >> 4) * 8;
#pragma unroll
    for (int j = 0; j < 8; ++j) {
        float x = U[(d0 + j) * DD + e];
        unsigned short hi = bf16_rne(x);
        float rem = x - __uint_as_float(((unsigned)hi) << 16);
        unsigned short lo = bf16_rne(rem);
        int idx = (blk * 64 + l) * 8 + j;
        Ufh[idx] = hi;
        Ufl[idx] = lo;
    }
}

// ---------------------------------------------------------------------------
// Main kernel. Row-decomposed: grid = 1024 blocks (b, rg), each block owns 16
// k-rows of one batch. 256 threads = 4 waves; wave w owns cols [32w, 32w+32).
// 4 blocks/CU -> 16 waves/CU; U frags = 64 VGPR/thread (fits 128-VGPR cap, no
// remat -> no per-step global U traffic).
// Per step: prefetch -> MFMA (24 acc + 3 gate-partial per wave, gpart to LDS)
// -> B2 -> redundant sigmoid, epilogue, sumsq partials -> B3 -> rsqrt,
// normalize, split-bf16 write to hA, stage next row -> B1.
// ---------------------------------------------------------------------------
__global__ __launch_bounds__(256, 4) void entnet_main(
    const float* __restrict__ enc,   // [B,S,D]
    const int*   __restrict__ mask,  // [B,S]
    const float* __restrict__ sWg,   // [B,S,D]
    const float* __restrict__ skg,   // [B,S,K]
    const float* __restrict__ kVg,   // [B,K,D]
    const unsigned short* __restrict__ Ufh,
    const unsigned short* __restrict__ Ufl,
    float*       __restrict__ out)   // [B,K,D]
{
    __shared__ __align__(16) unsigned short hAhi[4][64][8];   // 4 KB
    __shared__ __align__(16) unsigned short hAlo[4][64][8];   // 4 KB
    __shared__ __align__(16) unsigned short shi_sh[2][DD];
    __shared__ __align__(16) unsigned short slo_sh[2][DD];
    __shared__ __align__(16) float sW_sh[2][DD];
    __shared__ __align__(16) float sk_sh[2][16];
    __shared__ __align__(16) float gpart_sh[4][16];
    __shared__ __align__(16) float rowsq_sh[4][16];
    __shared__ int act_sh[SS];
    __shared__ int m_sh[SS];
    __shared__ int nact_sh;

    // XCD-grouped swizzle: 4 sibling blocks (same b) land on the same XCD.
    const int raw = blockIdx.x;
    const int xcd = raw & 7, slot = raw >> 3;
    const int b = xcd * 32 + (slot >> 2);
    const int rg = slot & 3;                 // row group: k in [16rg, 16rg+16)

    const int t = threadIdx.x;
    const int w = t >> 6, l = t & 63;
    const int gi = l >> 4, li = l & 15;
    const int slot_r = l ^ ((l >> 2) & 3);

    // ---- stage mask, zero hA ----
    if (t < SS) m_sh[t] = mask[b * SS + t];
    {
        unsigned int* p = (unsigned int*)&hAhi[0][0][0];
        unsigned int* q = (unsigned int*)&hAlo[0][0][0];
        for (int i = t; i < 4 * 64 * 8 / 2; i += 256) { p[i] = 0u; q[i] = 0u; }
    }
    __syncthreads();
    if (t == 0) {
        int c = 0;
        for (int i = 0; i < SS; ++i) if (m_sh[i]) act_sh[c++] = i;
        nact_sh = c;
    }

    // ---- U fragments (regs): ntg = 2w + nt, all kt ----
    bf16x8 ufh[2][4], ufl[2][4];
#pragma unroll
    for (int nt = 0; nt < 2; ++nt)
#pragma unroll
        for (int kt = 0; kt < 4; ++kt) {
            int off = (((2 * w + nt) * 4 + kt) * 64 + l) * 8;
            ufh[nt][kt] = *(const bf16x8*)&Ufh[off];
            ufl[nt][kt] = *(const bf16x8*)&Ufl[off];
        }
    // ---- kV (regs) ----
    float kvreg[2][4];
#pragma unroll
    for (int nt = 0; nt < 2; ++nt)
#pragma unroll
        for (int reg = 0; reg < 4; ++reg) {
            int k = 16 * rg + 4 * gi + reg;
            int e = 32 * w + 16 * nt + li;
            kvreg[nt][reg] = kVg[((size_t)b * KK + k) * DD + e];
        }
    f32x4 hreg[2];
    hreg[0] = (f32x4){0.f, 0.f, 0.f, 0.f};
    hreg[1] = (f32x4){0.f, 0.f, 0.f, 0.f};
    __syncthreads();

    const int nact = nact_sh;
    // ---- prologue: stage rows for act[0] into buffer 0 ----
    if (nact > 0) {
        int t0i = act_sh[0];
        if (t < 128) {
            float x = enc[((size_t)b * SS + t0i) * DD + t];
            unsigned u = __float_as_uint(x);
            shi_sh[0][t] = (unsigned short)(u >> 16);
            float rem = x - __uint_as_float(u & 0xffff0000u);
            slo_sh[0][t] = (unsigned short)(__float_as_uint(rem) >> 16);
        } else {
            sW_sh[0][t - 128] = sWg[((size_t)b * SS + t0i) * DD + (t - 128)];
        }
        if (t < 16) sk_sh[0][t] = skg[((size_t)b * SS + t0i) * KK + 16 * rg + t];
    }
    __syncthreads();

    for (int ai = 0; ai < nact; ++ai) {
        const int cur = ai & 1, nxt = cur ^ 1;
        // prefetch next active row (consumed after B3)
        float pf = 0.f, pfk = 0.f;
        const bool have = (ai + 1 < nact);
        if (have) {
            int tn = act_sh[ai + 1];
            if (t < 128) pf = enc[((size_t)b * SS + tn) * DD + t];
            else         pf = sWg[((size_t)b * SS + tn) * DD + (t - 128)];
            if (t < 16)  pfk = skg[((size_t)b * SS + tn) * KK + 16 * rg + t];
        }

        // ---- MFMA phase: acc = h@U (3-term split); gate partial for kt==w ----
        f32x4 acc0 = (f32x4){0.f, 0.f, 0.f, 0.f};
        f32x4 acc1 = (f32x4){0.f, 0.f, 0.f, 0.f};
        f32x4 gacc = (f32x4){0.f, 0.f, 0.f, 0.f};
#pragma unroll
        for (int kt = 0; kt < 4; ++kt) {
            bf16x8 ah = *(const bf16x8*)&hAhi[kt][slot_r][0];
            bf16x8 al = *(const bf16x8*)&hAlo[kt][slot_r][0];
            acc0 = __builtin_amdgcn_mfma_f32_16x16x32_bf16(ah, ufh[0][kt], acc0, 0, 0, 0);
            acc0 = __builtin_amdgcn_mfma_f32_16x16x32_bf16(al, ufh[0][kt], acc0, 0, 0, 0);
            acc0 = __builtin_amdgcn_mfma_f32_16x16x32_bf16(ah, ufl[0][kt], acc0, 0, 0, 0);
            acc1 = __builtin_amdgcn_mfma_f32_16x16x32_bf16(ah, ufh[1][kt], acc1, 0, 0, 0);
            acc1 = __builtin_amdgcn_mfma_f32_16x16x32_bf16(al, ufh[1][kt], acc1, 0, 0, 0);
            acc1 = __builtin_amdgcn_mfma_f32_16x16x32_bf16(ah, ufl[1][kt], acc1, 0, 0, 0);
            if (w == kt) {
                bf16x8 sh = *(const bf16x8*)&shi_sh[cur][32 * kt + 8 * gi];
                bf16x8 sl = *(const bf16x8*)&slo_sh[cur][32 * kt + 8 * gi];
                gacc = __builtin_amdgcn_mfma_f32_16x16x32_bf16(ah, sh, gacc, 0, 0, 0);
                gacc = __builtin_amdgcn_mfma_f32_16x16x32_bf16(al, sh, gacc, 0, 0, 0);
                gacc = __builtin_amdgcn_mfma_f32_16x16x32_bf16(ah, sl, gacc, 0, 0, 0);
            }
        }
        if (li == 0) *(f32x4*)&gpart_sh[w][4 * gi] = gacc;
        __syncthreads();  // B2: gpart visible; all hA/s reads done

        // ---- gate (redundant per thread) ----
        f32x4 gp = *(const f32x4*)&gpart_sh[0][4 * gi];
        gp += *(const f32x4*)&gpart_sh[1][4 * gi];
        gp += *(const f32x4*)&gpart_sh[2][4 * gi];
        gp += *(const f32x4*)&gpart_sh[3][4 * gi];
        f32x4 sk4 = *(const f32x4*)&sk_sh[cur][4 * gi];
        float g4[4];
#pragma unroll
        for (int reg = 0; reg < 4; ++reg)
            g4[reg] = 1.f / (1.f + __expf(-(gp[reg] + sk4[reg])));

        // ---- epilogue: upd = h + g*relu(acc+kV+sW), row sumsq partial ----
        float sw2[2] = { sW_sh[cur][32 * w + li], sW_sh[cur][32 * w + 16 + li] };
        f32x4 upd[2];
        float ss[4] = {0.f, 0.f, 0.f, 0.f};
#pragma unroll
        for (int reg = 0; reg < 4; ++reg) {
            float v0 = fmaxf(acc0[reg] + kvreg[0][reg] + sw2[0], 0.f);
            float u0 = fmaf(g4[reg], v0, hreg[0][reg]);
            upd[0][reg] = u0;
            float v1 = fmaxf(acc1[reg] + kvreg[1][reg] + sw2[1], 0.f);
            float u1 = fmaf(g4[reg], v1, hreg[1][reg]);
            upd[1][reg] = u1;
            ss[reg] = fmaf(u0, u0, fmaf(u1, u1, 0.f));
        }
#pragma unroll
        for (int m = 1; m < 16; m <<= 1)
#pragma unroll
            for (int reg = 0; reg < 4; ++reg) ss[reg] += __shfl_xor(ss[reg], m);
        if (li == 0) {
            f32x4 rr = {ss[0], ss[1], ss[2], ss[3]};
            *(f32x4*)&rowsq_sh[w][4 * gi] = rr;
        }
        __syncthreads();  // B3: all wave partials visible

        f32x4 rq = *(const f32x4*)&rowsq_sh[0][4 * gi];
        rq += *(const f32x4*)&rowsq_sh[1][4 * gi];
        rq += *(const f32x4*)&rowsq_sh[2][4 * gi];
        rq += *(const f32x4*)&rowsq_sh[3][4 * gi];
        float rinv[4];
#pragma unroll
        for (int reg = 0; reg < 4; ++reg)
            rinv[reg] = rsqrtf(fmaxf(rq[reg], 1e-12f));

        // ---- normalize, split bf16, write hA (own kt stripe = w) ----
#pragma unroll
        for (int nt = 0; nt < 2; ++nt) {
            int b23 = (2 * nt + (li >> 3)) & 3;
            int j = l & 7;
#pragma unroll
            for (int reg = 0; reg < 4; ++reg) {
                float hn = upd[nt][reg] * rinv[reg];
                hreg[nt][reg] = hn;
                unsigned u = __float_as_uint(hn);
                unsigned short hi = (unsigned short)(u >> 16);
                float rem = hn - __uint_as_float(u & 0xffff0000u);
                unsigned short lo = (unsigned short)(__float_as_uint(rem) >> 16);
                int le = (4 * gi + reg) | (b23 << 4);
                int slot_w = le ^ ((le >> 2) & 3);
                hAhi[w][slot_w][j] = hi;
                hAlo[w][slot_w][j] = lo;
            }
        }
        // ---- stage next row into buffer nxt ----
        if (have) {
            if (t < 128) {
                unsigned u = __float_as_uint(pf);
                shi_sh[nxt][t] = (unsigned short)(u >> 16);
                float rem = pf - __uint_as_float(u & 0xffff0000u);
                slo_sh[nxt][t] = (unsigned short)(__float_as_uint(rem) >> 16);
            } else {
                sW_sh[nxt][t - 128] = pf;
            }
            if (t < 16) sk_sh[nxt][t] = pfk;
        }
        __syncthreads();  // B1: hA + staged rows visible
    }

    // ---- final h -> out ----
#pragma unroll
    for (int nt = 0; nt < 2; ++nt)
#pragma unroll
        for (int reg = 0; reg < 4; ++reg) {
            int k = 16 * rg + 4 * gi + reg;
            int e = 32 * w + 16 * nt + li;
            out[((size_t)b * KK + k) * DD + e] = hreg[nt][reg];
        }
}

// ---------------------------------------------------------------------------
extern "C" void kernel_launch(void* const* d_in, const int* in_sizes, int n_in,
                              void* d_out, int out_size, void* d_ws, size_t ws_size,
                              hipStream_t stream)
{
    const float* enc  = (const float*)d_in[0];  // [B,S,D]
    const int*   mask = (const int*)  d_in[1];  // [B,S]
    const float* keys = (const float*)d_in[2];  // [B,K,D]
    const float* U    = (const float*)d_in[3];  // [D,D]
    const float* V    = (const float*)d_in[4];  // [D,D]
    const float* W    = (const float*)d_in[5];  // [D,D]
    float* out = (float*)d_out;

    // ws layout: sW [B,S,D] | sk [B,S,K] | kV [B,K,D] | Ufh | Ufl
    float* sW = (float*)d_ws;
    float* sk = sW + (size_t)BB * SS * DD;
    float* kV = sk + (size_t)BB * SS * KK;
    unsigned short* Ufh = (unsigned short*)(kV + (size_t)BB * KK * DD);
    unsigned short* Ufl = Ufh + 8 * 4 * 64 * 8;

    kv_kernel<<<BB, 256, 0, stream>>>(keys, V, kV);
    swsk_kernel<<<BB * 4, 256, 0, stream>>>(enc, W, keys, sW, sk);
    ufrag_kernel<<<32, 64, 0, stream>>>(U, Ufh, Ufl);
    entnet_main<<<BB * 4, 256, 0, stream>>>(enc, mask, sW, sk, kV, Ufh, Ufl, out);
}